// Round 1
// baseline (539.978 us; speedup 1.0000x reference)
//
#include <hip/hip_runtime.h>
#include <math.h>

// SparseDiffAttn: B=1,H=12,N=2048,D=128, BM=64, top-k=192, static window [c-153,c+153),
// random keys via modern-JAX randint under jax_threefry_partitionable=True:
//   k1 = tf((0,1),(0,0)), k2 = tf((0,1),(0,1))        [fold-like split]
//   bits(k,i) = b1^b2 with (b1,b2) = tf(k,(0,i))      [partitionable random_bits]
//   offset = ((hi%100)*96 + lo%100) % 100; rnd <=> offset==0
// PRECISION: selection robust to ~1e-6 rel (fp32==fp64 masks) but NOT fp16-E (R10, 5e-4).
// Split-fp16 MFMA QK (hi·hi + hi·lo + lo·hi) err ~1e-7 rel — inside the certified band.
// RULES LEARNED: (a) no register prefetch in k3 — R8/R13: destroys L2 reuse; barrier
// lockstep IS the reuse mechanism. (c) k3 XCD swizzle: FETCH 157->28MB.
// RULE (b) SUPERSEDED: "E materialization beats 2x QK recompute (R12)" was measured with
// SCALAR QK. With MFMA QK (~20us/pass), the 201MB g_E write + 201MB read (~290us at the
// ~1.1TB/s E-stream floor, R7/R9/R14/R15/R17) costs far more than a second QK pass.
// THIS ROUND: g_E eliminated. k1 = MFMA QK -> exp -> rowsum partials only (g_lp).
// k2r = MFMA QK recompute -> exp -> weight by 1/l -> in-register colsum -> g_bs.
// bs needs no cross-tile reduction (tile (h,gp,jb) owns bs[2 groups][128 cols]);
// only l crosses tiles, and it flows through g_lp exactly as before (bit-exact order).
constexpr int Hh   = 12;
constexpr int Nn   = 2048;
constexpr int Dd   = 128;
constexpr int BMq  = 64;
constexpr int QGg  = 32;            // Nn/BMq
constexpr int KSEL = 192;           // 64 * round(0.1*2048/64)
constexpr int CK   = 32;            // key chunk (k3)
constexpr float SCALE = 0.08838834764831845f;  // 1/sqrt(128)

typedef _Float16 v8h __attribute__((ext_vector_type(8)));   // MFMA A/B frag (4 VGPRs)
typedef float    v4f __attribute__((ext_vector_type(4)));   // MFMA C/D frag

// persistent scratch (fully rewritten every launch before any read)
__device__ float          g_lp[(size_t)Hh*Nn*16];           // per-jb partial row sums
__device__ float          g_bs[(size_t)Hh*QGg*Nn];          // colsum scores (3 MB)
__device__ unsigned short g_sel[Hh*QGg*Nn];
__device__ int            g_cnt[Hh*QGg];

__device__ __forceinline__ unsigned int rotl32(unsigned int x, int n){
  return (x << n) | (x >> (32 - n));
}

// threefry2x32, 20 rounds, arbitrary key
__device__ __forceinline__ void tf2x32(unsigned int k0, unsigned int k1,
                                       unsigned int x0, unsigned int x1,
                                       unsigned int &o0, unsigned int &o1){
  const unsigned int ks2 = 0x1BD11BDAu ^ k0 ^ k1;
  x0 += k0; x1 += k1;
  x0 += x1; x1 = rotl32(x1,13); x1 ^= x0;
  x0 += x1; x1 = rotl32(x1,15); x1 ^= x0;
  x0 += x1; x1 = rotl32(x1,26); x1 ^= x0;
  x0 += x1; x1 = rotl32(x1, 6); x1 ^= x0;
  x0 += k1; x1 += ks2 + 1u;
  x0 += x1; x1 = rotl32(x1,17); x1 ^= x0;
  x0 += x1; x1 = rotl32(x1,29); x1 ^= x0;
  x0 += x1; x1 = rotl32(x1,16); x1 ^= x0;
  x0 += x1; x1 = rotl32(x1,24); x1 ^= x0;
  x0 += ks2; x1 += k0 + 2u;
  x0 += x1; x1 = rotl32(x1,13); x1 ^= x0;
  x0 += x1; x1 = rotl32(x1,15); x1 ^= x0;
  x0 += x1; x1 = rotl32(x1,26); x1 ^= x0;
  x0 += x1; x1 = rotl32(x1, 6); x1 ^= x0;
  x0 += k0; x1 += k1 + 3u;
  x0 += x1; x1 = rotl32(x1,17); x1 ^= x0;
  x0 += x1; x1 = rotl32(x1,29); x1 ^= x0;
  x0 += x1; x1 = rotl32(x1,16); x1 ^= x0;
  x0 += x1; x1 = rotl32(x1,24); x1 ^= x0;
  x0 += k1; x1 += ks2 + 4u;
  x0 += x1; x1 = rotl32(x1,13); x1 ^= x0;
  x0 += x1; x1 = rotl32(x1,15); x1 ^= x0;
  x0 += x1; x1 = rotl32(x1,26); x1 ^= x0;
  x0 += x1; x1 = rotl32(x1, 6); x1 ^= x0;
  x0 += ks2; x1 += k0 + 5u;
  o0 = x0; o1 = x1;
}

// partitionable-threefry randint(key(1), ..., 0, 100) == 0 for flat element idx
__device__ __forceinline__ bool jax_rand01(unsigned int idx,
                                           unsigned int k1a, unsigned int k1b,
                                           unsigned int k2a, unsigned int k2b){
  unsigned int h0, h1, l0, l1;
  tf2x32(k1a, k1b, 0u, idx, h0, h1);
  tf2x32(k2a, k2b, 0u, idx, l0, l1);
  unsigned int h = h0 ^ h1;
  unsigned int l = l0 ^ l1;
  unsigned int off = ((h % 100u) * 96u + (l % 100u)) % 100u;
  return off == 0u;
}

// ---------------- Kernel 1: MFMA split-fp16 QK -> exp -> row-sum partials (NO E store) ----------------
// 128x128 tile per block, 4 waves x (2 tile-rows x 8 tile-cols) of 16x16x32_f16 MFMAs.
// A layout: lane holds A[m=lane&15][k=quad*8+j]; B: B[n=lane&15][k=quad*8+j];
// D layout (HW-verified m89/m91): col=lane&15, row=quad*4+reg. No LDS, no barriers.
__global__ __launch_bounds__(256) void k1_rowsum(const float* __restrict__ Q,
                                                 const float* __restrict__ K){
  const int bid = blockIdx.x;
  const int jb = bid & 15, gp = (bid >> 4) & 15, h = bid >> 8;
  const int t = threadIdx.x;
  const int wv = t >> 6, ln = t & 63;
  const int nidx = ln & 15, quad = ln >> 4;
  const int R0 = gp*128, J0 = jb*128;

  v4f acc[2][8];
  #pragma unroll
  for (int tr = 0; tr < 2; ++tr)
    #pragma unroll
    for (int tc = 0; tc < 8; ++tc)
      acc[tr][tc] = (v4f){0.f, 0.f, 0.f, 0.f};

  for (int kc = 0; kc < 4; ++kc){
    const int dofs = kc*32 + quad*8;
    v8h ahi[2], alo[2];
    #pragma unroll
    for (int tr = 0; tr < 2; ++tr){
      const float* qp = Q + ((size_t)h*Nn + R0 + (wv*2+tr)*16 + nidx)*Dd + dofs;
      float4 qa = *(const float4*)qp, qb = *(const float4*)(qp+4);
      float xs[8] = {qa.x,qa.y,qa.z,qa.w, qb.x,qb.y,qb.z,qb.w};
      #pragma unroll
      for (int j = 0; j < 8; ++j){
        float x = xs[j]*SCALE;
        _Float16 hi = (_Float16)x;
        ahi[tr][j] = hi;
        alo[tr][j] = (_Float16)(x - (float)hi);
      }
    }
    v8h bhi[8], blo[8];
    #pragma unroll
    for (int tc = 0; tc < 8; ++tc){
      const float* kp = K + ((size_t)h*Nn + J0 + tc*16 + nidx)*Dd + dofs;
      float4 ka = *(const float4*)kp, kb = *(const float4*)(kp+4);
      float xs[8] = {ka.x,ka.y,ka.z,ka.w, kb.x,kb.y,kb.z,kb.w};
      #pragma unroll
      for (int j = 0; j < 8; ++j){
        float x = xs[j];
        _Float16 hi = (_Float16)x;
        bhi[tc][j] = hi;
        blo[tc][j] = (_Float16)(x - (float)hi);
      }
    }
    #pragma unroll
    for (int tr = 0; tr < 2; ++tr)
      #pragma unroll
      for (int tc = 0; tc < 8; ++tc){
        acc[tr][tc] = __builtin_amdgcn_mfma_f32_16x16x32_f16(ahi[tr], bhi[tc], acc[tr][tc], 0, 0, 0);
        acc[tr][tc] = __builtin_amdgcn_mfma_f32_16x16x32_f16(ahi[tr], blo[tc], acc[tr][tc], 0, 0, 0);
        acc[tr][tc] = __builtin_amdgcn_mfma_f32_16x16x32_f16(alo[tr], bhi[tc], acc[tr][tc], 0, 0, 0);
      }
  }

  // epilogue: exp, shfl-reduced row sums -> g_lp (same accumulation order as before: bit-exact l)
  #pragma unroll
  for (int tr = 0; tr < 2; ++tr){
    float rs[4] = {0.f, 0.f, 0.f, 0.f};
    #pragma unroll
    for (int tc = 0; tc < 8; ++tc){
      #pragma unroll
      for (int r = 0; r < 4; ++r){
        rs[r] += __expf(acc[tr][tc][r]);
      }
    }
    #pragma unroll
    for (int r = 0; r < 4; ++r){
      float v = rs[r];
      v += __shfl_xor(v, 1);
      v += __shfl_xor(v, 2);
      v += __shfl_xor(v, 4);
      v += __shfl_xor(v, 8);
      rs[r] = v;
    }
    if (nidx == 0){
      #pragma unroll
      for (int r = 0; r < 4; ++r){
        const int row = (wv*2+tr)*16 + quad*4 + r;
        g_lp[((size_t)h*Nn + R0 + row)*16 + jb] = rs[r];
      }
    }
  }
}

// ---------------- Kernel 2r: MFMA QK recompute -> weighted colsum -> g_bs ----------------
// Same tile body as k1. Tile (h,gp,jb) owns bs[g=2gp..2gp+1][cols jb*128..+127]:
// no cross-tile reduction needed. il reduced from g_lp with x=0..15 ascending (bit-exact
// vs old k2a). Colsum: per-lane r-sum -> quad butterfly (xor16,xor32) -> tr -> wave pair.
__global__ __launch_bounds__(256) void k2r_colsum(const float* __restrict__ Q,
                                                  const float* __restrict__ K){
  const int bid = blockIdx.x;
  const int jb = bid & 15, gp = (bid >> 4) & 15, h = bid >> 8;
  const int t = threadIdx.x;
  const int wv = t >> 6, ln = t & 63;
  const int nidx = ln & 15, quad = ln >> 4;
  const int R0 = gp*128, J0 = jb*128;

  __shared__ float il_s[128];
  __shared__ float part[4][128];
  if (t < 128){
    const float* lp = &g_lp[((size_t)h*Nn + R0 + t)*16];
    float s = 0.f;
    #pragma unroll
    for (int x = 0; x < 16; ++x) s += lp[x];
    il_s[t] = 1.0f / s;
  }
  __syncthreads();

  v4f acc[2][8];
  #pragma unroll
  for (int tr = 0; tr < 2; ++tr)
    #pragma unroll
    for (int tc = 0; tc < 8; ++tc)
      acc[tr][tc] = (v4f){0.f, 0.f, 0.f, 0.f};

  for (int kc = 0; kc < 4; ++kc){
    const int dofs = kc*32 + quad*8;
    v8h ahi[2], alo[2];
    #pragma unroll
    for (int tr = 0; tr < 2; ++tr){
      const float* qp = Q + ((size_t)h*Nn + R0 + (wv*2+tr)*16 + nidx)*Dd + dofs;
      float4 qa = *(const float4*)qp, qb = *(const float4*)(qp+4);
      float xs[8] = {qa.x,qa.y,qa.z,qa.w, qb.x,qb.y,qb.z,qb.w};
      #pragma unroll
      for (int j = 0; j < 8; ++j){
        float x = xs[j]*SCALE;
        _Float16 hi = (_Float16)x;
        ahi[tr][j] = hi;
        alo[tr][j] = (_Float16)(x - (float)hi);
      }
    }
    v8h bhi[8], blo[8];
    #pragma unroll
    for (int tc = 0; tc < 8; ++tc){
      const float* kp = K + ((size_t)h*Nn + J0 + tc*16 + nidx)*Dd + dofs;
      float4 ka = *(const float4*)kp, kb = *(const float4*)(kp+4);
      float xs[8] = {ka.x,ka.y,ka.z,ka.w, kb.x,kb.y,kb.z,kb.w};
      #pragma unroll
      for (int j = 0; j < 8; ++j){
        float x = xs[j];
        _Float16 hi = (_Float16)x;
        bhi[tc][j] = hi;
        blo[tc][j] = (_Float16)(x - (float)hi);
      }
    }
    #pragma unroll
    for (int tr = 0; tr < 2; ++tr)
      #pragma unroll
      for (int tc = 0; tc < 8; ++tc){
        acc[tr][tc] = __builtin_amdgcn_mfma_f32_16x16x32_f16(ahi[tr], bhi[tc], acc[tr][tc], 0, 0, 0);
        acc[tr][tc] = __builtin_amdgcn_mfma_f32_16x16x32_f16(ahi[tr], blo[tc], acc[tr][tc], 0, 0, 0);
        acc[tr][tc] = __builtin_amdgcn_mfma_f32_16x16x32_f16(alo[tr], bhi[tc], acc[tr][tc], 0, 0, 0);
      }
  }

  // weighted colsum epilogue. Wave wv covers tile rows [wv*32, wv*32+32).
  float csg[8];
  #pragma unroll
  for (int tc = 0; tc < 8; ++tc) csg[tc] = 0.f;
  #pragma unroll
  for (int tr = 0; tr < 2; ++tr){
    #pragma unroll
    for (int tc = 0; tc < 8; ++tc){
      float cs = 0.f;
      #pragma unroll
      for (int r = 0; r < 4; ++r){
        const int row = (wv*2+tr)*16 + quad*4 + r;
        cs += __expf(acc[tr][tc][r]) * il_s[row];
      }
      cs += __shfl_xor(cs, 16);   // sum across the 4 quads (16 rows of this tile-row)
      cs += __shfl_xor(cs, 32);
      csg[tc] += cs;
    }
  }
  if (ln < 16){                    // quad 0 publishes this wave's 128 col-partials
    #pragma unroll
    for (int tc = 0; tc < 8; ++tc) part[wv][tc*16 + nidx] = csg[tc];
  }
  __syncthreads();
  // waves 0+1 = rows 0..63 = group 2gp; waves 2+3 = group 2gp+1
  const int col = t & 127, grp = t >> 7;
  g_bs[((size_t)h*QGg + gp*2 + grp)*Nn + jb*128 + col] =
      part[grp*2][col] + part[grp*2 + 1][col];
}

// ---------------- Kernel 2b: top-k + random + static window -> compacted key list ----------------
__global__ __launch_bounds__(256) void k2b_mask(){
  const int bid = blockIdx.x, g = bid % QGg, t = threadIdx.x;
  __shared__ float bsv[Nn];
  __shared__ int red[33];
  __shared__ int csel;
  const float* src = g_bs + (size_t)bid*Nn;
  float mine[8];
  {
    float4 a = *(const float4*)&src[t*4];
    float4 b = *(const float4*)&src[1024 + t*4];
    *(float4*)&bsv[t*4] = a;
    *(float4*)&bsv[1024 + t*4] = b;
    mine[0]=a.x; mine[1]=a.y; mine[2]=a.z; mine[3]=a.w;
    mine[4]=b.x; mine[5]=b.y; mine[6]=b.z; mine[7]=b.w;
  }
  if (t < 33) red[t] = 0;
  if (t == 0) csel = 0;
  __syncthreads();

  unsigned int k1a, k1b, k2a, k2b;
  tf2x32(0u, 1u, 0u, 0u, k1a, k1b);
  tf2x32(0u, 1u, 0u, 1u, k2a, k2b);

  // 192nd-largest via bitwise binary search (positive -> uint order)
  unsigned int prefix = 0u;
  for (int bit = 31; bit >= 0; --bit){
    unsigned int cand = prefix | (1u << bit);
    int c = 0;
    #pragma unroll
    for (int u = 0; u < 8; ++u)
      c += (__float_as_uint(mine[u]) >= cand) ? 1 : 0;
    #pragma unroll
    for (int off = 32; off > 0; off >>= 1) c += __shfl_down(c, off);
    if ((t & 63) == 0) atomicAdd(&red[bit], c);
    __syncthreads();
    if (red[bit] >= KSEL) prefix = cand;
  }
  {
    int cg = 0;
    #pragma unroll
    for (int u = 0; u < 8; ++u)
      cg += (__float_as_uint(mine[u]) > prefix) ? 1 : 0;
    #pragma unroll
    for (int off = 32; off > 0; off >>= 1) cg += __shfl_down(cg, off);
    if ((t & 63) == 0) atomicAdd(&red[32], cg);
  }
  __syncthreads();
  const int need = KSEL - red[32];   // ties taken lowest-index-first (jax top_k)

  const int lo = g*BMq + BMq/2 - 153;   // ws=int(0.15*2048)=307, ws//2=153
  const int hi = g*BMq + BMq/2 + 153;
  const int ssum = ((hi < Nn) ? hi : Nn) - ((lo > 0) ? lo : 0);
  const bool vqg = (ssum + KSEL) < Nn;  // always true at this config

  #pragma unroll
  for (int u = 0; u < 8; ++u){
    int j = (u < 4) ? (t*4 + u) : (1024 + t*4 + u - 4);
    unsigned int bu = __float_as_uint(mine[u]);
    bool topk = bu > prefix;
    if (!topk && bu == prefix){
      int tr = 0;
      for (int jj = 0; jj < j; ++jj)
        tr += (__float_as_uint(bsv[jj]) == prefix) ? 1 : 0;
      topk = (tr < need);
    }
    bool rnd = jax_rand01((unsigned)(bid*Nn + j), k1a, k1b, k2a, k2b);
    bool st  = (j >= lo) && (j < hi);
    bool selb = st || ((rnd || topk) && vqg);
    if (selb){
      int slot = atomicAdd(&csel, 1);
      g_sel[(size_t)bid*Nn + slot] = (unsigned short)j;
    }
  }
  __syncthreads();
  if (t == 0) g_cnt[bid] = csel;
}

// ---------------- Kernel 3: one-pass attention, XCD-swizzled, NO prefetch ----------------
__global__ __launch_bounds__(256) void k3_attn(const float* __restrict__ Q,
                                               const float* __restrict__ K,
                                               const float* __restrict__ V,
                                               const float* __restrict__ OC,
                                               float* __restrict__ out){
  const int bid0 = blockIdx.x;
  const int w    = (bid0 & 7)*96 + (bid0 >> 3);   // xcd-grouped work index
  const int half = w & 1;
  const int gg   = w >> 1;             // h*QGg + g
  const int h = gg / QGg, g = gg % QGg;
  const int t = threadIdx.x;
  __shared__ float q_s[32][Dd+4];
  __shared__ float kv_s[CK][Dd+4];
  __shared__ float s_s[32][CK+1];
  __shared__ float l_s[32];
  const int c = g_cnt[gg];
  const unsigned short* sel = g_sel + (size_t)gg*Nn;

  const float* qb = Q + ((size_t)h*Nn + (size_t)g*BMq + half*32)*Dd;
  #pragma unroll
  for (int it = 0; it < 4; ++it){
    int e = it*256 + t;                 // 1024 float4s = 32 rows x 32 f4
    int row = e >> 5, c4 = e & 31;
    float4 vq = ((const float4*)qb)[e];
    float4 sv; sv.x = vq.x*SCALE; sv.y = vq.y*SCALE; sv.z = vq.z*SCALE; sv.w = vq.w*SCALE;
    *(float4*)&q_s[row][c4*4] = sv;
  }
  if (t < 32) l_s[t] = 0.0f;
  __syncthreads();

  const int rt = t & 15, kcol = (t >> 4)*2;
  const int d0 = (t >> 4)*8;           // PV column group
  float acc2[2][8] = {};

  for (int c0 = 0; c0 < c; c0 += CK){
    const int cc = ((c - c0) < CK) ? (c - c0) : CK;
    // gather K chunk
    #pragma unroll
    for (int it = 0; it < 4; ++it){
      int e = it*256 + t, row = e >> 5, c4 = e & 31;
      int j = (row < cc) ? (int)sel[c0 + row] : 0;
      *(float4*)&kv_s[row][c4*4] = ((const float4*)(K + ((size_t)h*Nn + j)*Dd))[c4];
    }
    __syncthreads();
    float a00=0.f, a01=0.f, a10=0.f, a11=0.f;
    #pragma unroll 8
    for (int d = 0; d < Dd; d += 4){
      float4 k0 = *(const float4*)&kv_s[kcol][d];
      float4 k1 = *(const float4*)&kv_s[kcol+1][d];
      float4 q0 = *(const float4*)&q_s[rt][d];
      float4 q1 = *(const float4*)&q_s[rt+16][d];
      a00 += q0.x*k0.x + q0.y*k0.y + q0.z*k0.z + q0.w*k0.w;
      a01 += q0.x*k1.x + q0.y*k1.y + q0.z*k1.z + q0.w*k1.w;
      a10 += q1.x*k0.x + q1.y*k0.y + q1.z*k0.z + q1.w*k0.w;
      a11 += q1.x*k1.x + q1.y*k1.y + q1.z*k1.z + q1.w*k1.w;
    }
    s_s[rt   ][kcol  ] = (kcol   < cc) ? __expf(a00) : 0.f;
    s_s[rt   ][kcol+1] = (kcol+1 < cc) ? __expf(a01) : 0.f;
    s_s[rt+16][kcol  ] = (kcol   < cc) ? __expf(a10) : 0.f;
    s_s[rt+16][kcol+1] = (kcol+1 < cc) ? __expf(a11) : 0.f;
    __syncthreads();
    if (t < 32){
      float s = 0.f;
      #pragma unroll
      for (int c2 = 0; c2 < CK; ++c2) s += s_s[t][c2];
      l_s[t] += s;
    }
    // gather V chunk (overwrites kv_s; QK readers already past barrier)
    #pragma unroll
    for (int it = 0; it < 4; ++it){
      int e = it*256 + t, row = e >> 5, c4 = e & 31;
      int j = (row < cc) ? (int)sel[c0 + row] : 0;
      *(float4*)&kv_s[row][c4*4] = ((const float4*)(V + ((size_t)h*Nn + j)*Dd))[c4];
    }
    __syncthreads();
    for (int c2 = 0; c2 < cc; ++c2){
      float p0 = s_s[rt][c2], p1 = s_s[rt+16][c2];
      float4 va = *(const float4*)&kv_s[c2][d0];
      float4 vb = *(const float4*)&kv_s[c2][d0+4];
      acc2[0][0] += p0*va.x; acc2[0][1] += p0*va.y;
      acc2[0][2] += p0*va.z; acc2[0][3] += p0*va.w;
      acc2[0][4] += p0*vb.x; acc2[0][5] += p0*vb.y;
      acc2[0][6] += p0*vb.z; acc2[0][7] += p0*vb.w;
      acc2[1][0] += p1*va.x; acc2[1][1] += p1*va.y;
      acc2[1][2] += p1*va.z; acc2[1][3] += p1*va.w;
      acc2[1][4] += p1*vb.x; acc2[1][5] += p1*vb.y;
      acc2[1][6] += p1*vb.z; acc2[1][7] += p1*vb.w;
    }
    __syncthreads();
  }

  if (t < 32) l_s[t] = 1.0f / l_s[t];
  __syncthreads();

  #pragma unroll
  for (int rr = 0; rr < 2; ++rr){
    const int r = rr*16 + rt;
    const float il = l_s[r];
    size_t o = ((size_t)h*Nn + (size_t)g*BMq + half*32 + r)*Dd + d0;
    float4 ca = *(const float4*)(OC + o);
    float4 cb = *(const float4*)(OC + o + 4);
    float4 ra, rb;
    ra.x = acc2[rr][0]*il + ca.x; ra.y = acc2[rr][1]*il + ca.y;
    ra.z = acc2[rr][2]*il + ca.z; ra.w = acc2[rr][3]*il + ca.w;
    rb.x = acc2[rr][4]*il + cb.x; rb.y = acc2[rr][5]*il + cb.y;
    rb.z = acc2[rr][6]*il + cb.z; rb.w = acc2[rr][7]*il + cb.w;
    *(float4*)(out + o)     = ra;
    *(float4*)(out + o + 4) = rb;
  }
}

extern "C" void kernel_launch(void* const* d_in, const int* in_sizes, int n_in,
                              void* d_out, int out_size, void* d_ws, size_t ws_size,
                              hipStream_t stream) {
  (void)in_sizes; (void)n_in; (void)out_size; (void)d_ws; (void)ws_size;
  const float* Q  = (const float*)d_in[0];
  const float* K  = (const float*)d_in[1];
  const float* V  = (const float*)d_in[2];
  const float* OC = (const float*)d_in[3];
  float* out = (float*)d_out;
  hipLaunchKernelGGL(k1_rowsum,  dim3(Hh*16*16),  dim3(256), 0, stream, Q, K);
  hipLaunchKernelGGL(k2r_colsum, dim3(Hh*16*16),  dim3(256), 0, stream, Q, K);
  hipLaunchKernelGGL(k2b_mask,   dim3(Hh*QGg),    dim3(256), 0, stream);
  hipLaunchKernelGGL(k3_attn,    dim3(Hh*QGg*2),  dim3(256), 0, stream, Q, K, V, OC, out);
}